// Round 1
// baseline (637.460 us; speedup 1.0000x reference)
//
#include <hip/hip_runtime.h>
#include <math.h>

// Problem constants (fixed by the reference): B=8, C=D=512, H=W=128
#define BB   8
#define CC   512
#define DD   512
#define HW   16384
#define HW4  4096    // HW / 4 (float4 count per (b,c) row)

// Algebraic restructuring (query length == 1):
//   logits = (q@Wk)·x  (+ q·bk, dropped: softmax shift-invariant)
//   gate   = Wv·(attn-pooled x) + bv   (since sum(attn)==1)
// => k and v are never materialized; the kernel is HBM-streaming-bound:
//    3 reads of x + 1 write of out ≈ 1.07 GB.

// ---- A: q[b,c] = context[b,:]·Wq[c,:] + bq[c]   (tiny) ----
__global__ __launch_bounds__(256) void k_qproj(const float* __restrict__ ctx,
                                               const float* __restrict__ Wq,
                                               const float* __restrict__ bq,
                                               float* __restrict__ q) {
    int t = blockIdx.x * 256 + threadIdx.x;       // 0..4095
    int b = t >> 9, c = t & (CC - 1);
    const float4* cr = (const float4*)(ctx + (size_t)b * DD);
    const float4* wr = (const float4*)(Wq + (size_t)c * DD);
    float acc = 0.f;
    #pragma unroll 8
    for (int d = 0; d < DD / 4; ++d) {
        float4 a = cr[d], w = wr[d];
        acc += a.x * w.x + a.y * w.y + a.z * w.z + a.w * w.w;
    }
    q[t] = acc + bq[c];
}

// ---- B: qk[b,c] = sum_o q[b,o] * Wk[o,c]   (tiny, coalesced over c) ----
__global__ __launch_bounds__(256) void k_qk(const float* __restrict__ q,
                                            const float* __restrict__ Wk,
                                            float* __restrict__ qk) {
    __shared__ float qs[CC];
    int b = blockIdx.x >> 1;                      // 2 blocks per batch
    int c = (blockIdx.x & 1) * 256 + threadIdx.x;
    for (int i = threadIdx.x; i < CC; i += 256) qs[i] = q[b * CC + i];
    __syncthreads();
    float acc = 0.f;
    #pragma unroll 8
    for (int o = 0; o < CC; ++o) acc += qs[o] * Wk[(size_t)o * CC + c];
    qk[b * CC + c] = acc;
}

// ---- C: logits[b,hw] = scale * sum_c qk[b,c]*x[b,c,hw]   (reads x: 268 MB) ----
__global__ __launch_bounds__(64) void k_logits(const float* __restrict__ x,
                                               const float* __restrict__ qk,
                                               float* __restrict__ logits) {
    __shared__ float qs[CC];
    int b   = blockIdx.x >> 6;                    // 64 blocks per batch
    int hw4 = (blockIdx.x & 63) * 64 + threadIdx.x;
    for (int i = threadIdx.x; i < CC; i += 64) qs[i] = qk[b * CC + i];
    __syncthreads();
    const float4* x4 = (const float4*)x;
    size_t base = (size_t)b * CC * HW4 + hw4;
    float ax = 0.f, ay = 0.f, az = 0.f, aw = 0.f;
    #pragma unroll 4
    for (int c = 0; c < CC; ++c) {
        float4 v = x4[base + (size_t)c * HW4];
        float w = qs[c];
        ax += w * v.x; ay += w * v.y; az += w * v.z; aw += w * v.w;
    }
    const float scale = 0.04419417382415922f;     // 512^-0.5
    float4 o = { ax * scale, ay * scale, az * scale, aw * scale };
    ((float4*)logits)[(size_t)b * HW4 + hw4] = o;
}

// ---- D: softmax over HW, in place (one block per batch, 1024 threads) ----
__global__ __launch_bounds__(1024) void k_softmax(float* __restrict__ buf) {
    int b = blockIdx.x, tid = threadIdx.x;
    float4* p4 = (float4*)(buf + (size_t)b * HW);
    float4 v[4];
    float m = -1e30f;
    #pragma unroll
    for (int i = 0; i < 4; ++i) {
        v[i] = p4[tid + i * 1024];
        m = fmaxf(m, fmaxf(fmaxf(v[i].x, v[i].y), fmaxf(v[i].z, v[i].w)));
    }
    __shared__ float redm[16], reds[16];
    for (int off = 32; off; off >>= 1) m = fmaxf(m, __shfl_down(m, off));
    if ((tid & 63) == 0) redm[tid >> 6] = m;
    __syncthreads();
    if (tid < 64) {                               // full wave active -> shfl defined
        float mm = (tid < 16) ? redm[tid] : -1e30f;
        for (int off = 8; off; off >>= 1) mm = fmaxf(mm, __shfl_down(mm, off));
        if (tid == 0) redm[0] = mm;
    }
    __syncthreads();
    m = redm[0];
    float s = 0.f;
    #pragma unroll
    for (int i = 0; i < 4; ++i) {
        v[i].x = expf(v[i].x - m); v[i].y = expf(v[i].y - m);
        v[i].z = expf(v[i].z - m); v[i].w = expf(v[i].w - m);
        s += v[i].x + v[i].y + v[i].z + v[i].w;
    }
    for (int off = 32; off; off >>= 1) s += __shfl_down(s, off);
    if ((tid & 63) == 0) reds[tid >> 6] = s;
    __syncthreads();
    if (tid < 64) {
        float ss = (tid < 16) ? reds[tid] : 0.f;
        for (int off = 8; off; off >>= 1) ss += __shfl_down(ss, off);
        if (tid == 0) reds[0] = ss;
    }
    __syncthreads();
    float inv = 1.f / reds[0];
    #pragma unroll
    for (int i = 0; i < 4; ++i) {
        float4 o = { v[i].x * inv, v[i].y * inv, v[i].z * inv, v[i].w * inv };
        p4[tid + i * 1024] = o;
    }
}

// ---- E: pooled[b,c] = sum_hw attn[b,hw]*x[b,c,hw]   (reads x: 268 MB) ----
__global__ __launch_bounds__(256) void k_pool(const float* __restrict__ x,
                                              const float* __restrict__ attn,
                                              float* __restrict__ pooled) {
    int bc = blockIdx.x;                          // 0..4095
    int b  = bc >> 9;
    int tid = threadIdx.x;
    const float4* xr = (const float4*)x    + (size_t)bc * HW4;
    const float4* ar = (const float4*)attn + (size_t)b  * HW4;
    float acc = 0.f;
    #pragma unroll 4
    for (int i = tid; i < HW4; i += 256) {
        float4 xv = xr[i], av = ar[i];            // attn row is L2-resident (64 KB/b)
        acc += xv.x * av.x + xv.y * av.y + xv.z * av.z + xv.w * av.w;
    }
    for (int off = 32; off; off >>= 1) acc += __shfl_down(acc, off);
    __shared__ float red[4];
    if ((tid & 63) == 0) red[tid >> 6] = acc;
    __syncthreads();
    if (tid == 0) pooled[bc] = red[0] + red[1] + red[2] + red[3];
}

// ---- F: gate[b,o] = Wv[o,:]·pooled[b,:] + bv[o]   (tiny) ----
__global__ __launch_bounds__(256) void k_gate(const float* __restrict__ pooled,
                                              const float* __restrict__ Wv,
                                              const float* __restrict__ bv,
                                              float* __restrict__ gate) {
    int t = blockIdx.x * 256 + threadIdx.x;       // 0..4095
    int b = t >> 9, o = t & (CC - 1);
    const float4* pr = (const float4*)(pooled + (size_t)b * CC);
    const float4* wr = (const float4*)(Wv + (size_t)o * CC);
    float acc = 0.f;
    #pragma unroll 8
    for (int i = 0; i < CC / 4; ++i) {
        float4 p = pr[i], w = wr[i];
        acc += p.x * w.x + p.y * w.y + p.z * w.z + p.w * w.w;
    }
    gate[t] = acc + bv[o];
}

// ---- G: out[b,c,hw] = x[b,c,hw] * gate[b,c]   (read+write: 536 MB) ----
__global__ __launch_bounds__(256) void k_out(const float* __restrict__ x,
                                             const float* __restrict__ gate,
                                             float* __restrict__ out) {
    const float4* x4 = (const float4*)x;
    float4* o4 = (float4*)out;
    size_t stride = (size_t)gridDim.x * blockDim.x;
    size_t total  = (size_t)BB * CC * HW4;
    for (size_t i = (size_t)blockIdx.x * blockDim.x + threadIdx.x; i < total; i += stride) {
        float g = gate[i >> 12];                  // gate is 16 KB, cache-resident
        float4 v = x4[i];
        float4 o = { v.x * g, v.y * g, v.z * g, v.w * g };
        o4[i] = o;
    }
}

extern "C" void kernel_launch(void* const* d_in, const int* in_sizes, int n_in,
                              void* d_out, int out_size, void* d_ws, size_t ws_size,
                              hipStream_t stream) {
    const float* x   = (const float*)d_in[0];
    const float* ctx = (const float*)d_in[1];
    const float* Wq  = (const float*)d_in[2];
    const float* bq  = (const float*)d_in[3];
    const float* Wk  = (const float*)d_in[4];
    // d_in[5] = bk: contributes a per-batch constant to logits -> dropped (softmax shift-invariant)
    const float* Wv  = (const float*)d_in[6];
    const float* bv  = (const float*)d_in[7];
    float* out = (float*)d_out;

    // Workspace layout (floats): everything written before read, no zero-init needed.
    float* ws     = (float*)d_ws;
    float* q      = ws;                 // 4096
    float* qk     = ws + 4096;          // 4096
    float* pooled = ws + 8192;          // 4096
    float* gate   = ws + 12288;         // 4096
    float* logits = ws + 16384;         // 131072 (softmax runs in place -> attn)

    k_qproj  <<<  16, 256, 0, stream>>>(ctx, Wq, bq, q);
    k_qk     <<<  16, 256, 0, stream>>>(q, Wk, qk);
    k_logits <<< 512,  64, 0, stream>>>(x, qk, logits);
    k_softmax<<<  BB,1024, 0, stream>>>(logits);          // in place: logits -> attn
    k_pool   <<<4096, 256, 0, stream>>>(x, logits, pooled);
    k_gate   <<<  16, 256, 0, stream>>>(pooled, Wv, bv, gate);
    k_out    <<<2048, 256, 0, stream>>>(x, gate, out);
}

// Round 2
// 618.880 us; speedup vs baseline: 1.0300x; 1.0300x over previous
//
#include <hip/hip_runtime.h>
#include <math.h>

// Problem constants (fixed by the reference): B=8, C=D=512, H=W=128
#define BB   8
#define CC   512
#define DD   512
#define HW   16384
#define HW4  4096    // HW / 4 (float4 count per (b,c) row)

// Algebraic restructuring (query length == 1):
//   logits = (q@Wk)·x  (+ q·bk, dropped: softmax shift-invariant)
//   gate   = Wv·(attn-pooled x) + bv   (since sum(attn)==1)
// => k and v are never materialized; 3 reads of x + 1 write of out ≈ 1.07 GB
//    at 6.3 TB/s achievable => ~170 µs floor + small-kernel overhead.

// ---- A: q[b,c] = context[b,:]·Wq[c,:] + bq[c]   (tiny) ----
__global__ __launch_bounds__(256) void k_qproj(const float* __restrict__ ctx,
                                               const float* __restrict__ Wq,
                                               const float* __restrict__ bq,
                                               float* __restrict__ q) {
    int t = blockIdx.x * 256 + threadIdx.x;       // 0..4095
    int b = t >> 9, c = t & (CC - 1);
    const float4* cr = (const float4*)(ctx + (size_t)b * DD);
    const float4* wr = (const float4*)(Wq + (size_t)c * DD);
    float acc = 0.f;
    #pragma unroll 8
    for (int d = 0; d < DD / 4; ++d) {
        float4 a = cr[d], w = wr[d];
        acc += a.x * w.x + a.y * w.y + a.z * w.z + a.w * w.w;
    }
    q[t] = acc + bq[c];
}

// ---- B: qk[b,c] = sum_o q[b,o] * Wk[o,c]   (tiny, coalesced over c) ----
__global__ __launch_bounds__(256) void k_qk(const float* __restrict__ q,
                                            const float* __restrict__ Wk,
                                            float* __restrict__ qk) {
    __shared__ float qs[CC];
    int b = blockIdx.x >> 1;                      // 2 blocks per batch
    int c = (blockIdx.x & 1) * 256 + threadIdx.x;
    for (int i = threadIdx.x; i < CC; i += 256) qs[i] = q[b * CC + i];
    __syncthreads();
    float acc = 0.f;
    #pragma unroll 8
    for (int o = 0; o < CC; ++o) acc += qs[o] * Wk[(size_t)o * CC + c];
    qk[b * CC + c] = acc;
}

// ---- C: logits[b,hw] = scale * sum_c qk[b,c]*x[b,c,hw]   (reads x: 268 MB) ----
// 512 blocks x 4 waves: wave w reduces channels [128w, 128w+128), LDS-combine.
// 2048 waves = 8 waves/CU -> enough MLP to be HBM-bound (was 2 waves/CU).
__global__ __launch_bounds__(256) void k_logits(const float* __restrict__ x,
                                                const float* __restrict__ qk,
                                                float* __restrict__ logits) {
    __shared__ float qs[CC];
    __shared__ float4 part[3][64];
    int b       = blockIdx.x >> 6;                // 64 blocks per batch
    int hwchunk = blockIdx.x & 63;
    int wave = threadIdx.x >> 6, lane = threadIdx.x & 63;
    int hw4 = hwchunk * 64 + lane;
    for (int i = threadIdx.x; i < CC; i += 256) qs[i] = qk[b * CC + i];
    __syncthreads();
    const float4* x4 = (const float4*)x;
    size_t base = (size_t)b * CC * HW4 + (size_t)(wave * 128) * HW4 + hw4;
    float ax = 0.f, ay = 0.f, az = 0.f, aw = 0.f;
    #pragma unroll 8
    for (int c = 0; c < 128; ++c) {
        float4 v = x4[base + (size_t)c * HW4];
        float w = qs[wave * 128 + c];
        ax += w * v.x; ay += w * v.y; az += w * v.z; aw += w * v.w;
    }
    if (wave > 0) {
        float4 p = { ax, ay, az, aw };
        part[wave - 1][lane] = p;
    }
    __syncthreads();
    if (wave == 0) {
        #pragma unroll
        for (int w2 = 0; w2 < 3; ++w2) {
            float4 p = part[w2][lane];
            ax += p.x; ay += p.y; az += p.z; aw += p.w;
        }
        const float scale = 0.04419417382415922f; // 512^-0.5
        float4 o = { ax * scale, ay * scale, az * scale, aw * scale };
        ((float4*)logits)[(size_t)b * HW4 + hw4] = o;
    }
}

// ---- D: softmax over HW, in place (one block per batch, 1024 threads) ----
__global__ __launch_bounds__(1024) void k_softmax(float* __restrict__ buf) {
    int b = blockIdx.x, tid = threadIdx.x;
    float4* p4 = (float4*)(buf + (size_t)b * HW);
    float4 v[4];
    float m = -1e30f;
    #pragma unroll
    for (int i = 0; i < 4; ++i) {
        v[i] = p4[tid + i * 1024];
        m = fmaxf(m, fmaxf(fmaxf(v[i].x, v[i].y), fmaxf(v[i].z, v[i].w)));
    }
    __shared__ float redm[16], reds[16];
    for (int off = 32; off; off >>= 1) m = fmaxf(m, __shfl_down(m, off));
    if ((tid & 63) == 0) redm[tid >> 6] = m;
    __syncthreads();
    if (tid < 64) {                               // full wave active -> shfl defined
        float mm = (tid < 16) ? redm[tid] : -1e30f;
        for (int off = 8; off; off >>= 1) mm = fmaxf(mm, __shfl_down(mm, off));
        if (tid == 0) redm[0] = mm;
    }
    __syncthreads();
    m = redm[0];
    float s = 0.f;
    #pragma unroll
    for (int i = 0; i < 4; ++i) {
        v[i].x = expf(v[i].x - m); v[i].y = expf(v[i].y - m);
        v[i].z = expf(v[i].z - m); v[i].w = expf(v[i].w - m);
        s += v[i].x + v[i].y + v[i].z + v[i].w;
    }
    for (int off = 32; off; off >>= 1) s += __shfl_down(s, off);
    if ((tid & 63) == 0) reds[tid >> 6] = s;
    __syncthreads();
    if (tid < 64) {
        float ss = (tid < 16) ? reds[tid] : 0.f;
        for (int off = 8; off; off >>= 1) ss += __shfl_down(ss, off);
        if (tid == 0) reds[0] = ss;
    }
    __syncthreads();
    float inv = 1.f / reds[0];
    #pragma unroll
    for (int i = 0; i < 4; ++i) {
        float4 o = { v[i].x * inv, v[i].y * inv, v[i].z * inv, v[i].w * inv };
        p4[tid + i * 1024] = o;
    }
}

// ---- E: pooled[b,c] = sum_hw attn[b,hw]*x[b,c,hw]   (reads x: 268 MB) ----
__global__ __launch_bounds__(256) void k_pool(const float* __restrict__ x,
                                              const float* __restrict__ attn,
                                              float* __restrict__ pooled) {
    int bc = blockIdx.x;                          // 0..4095, one (b,c) row each
    int b  = bc >> 9;
    int tid = threadIdx.x;
    const float4* xr = (const float4*)x    + (size_t)bc * HW4;
    const float4* ar = (const float4*)attn + (size_t)b  * HW4;
    float acc = 0.f;
    #pragma unroll 8
    for (int i = tid; i < HW4; i += 256) {
        float4 xv = xr[i], av = ar[i];            // attn row is L2/L3-resident
        acc += xv.x * av.x + xv.y * av.y + xv.z * av.z + xv.w * av.w;
    }
    for (int off = 32; off; off >>= 1) acc += __shfl_down(acc, off);
    __shared__ float red[4];
    if ((tid & 63) == 0) red[tid >> 6] = acc;
    __syncthreads();
    if (tid == 0) pooled[bc] = red[0] + red[1] + red[2] + red[3];
}

// ---- F: gate[b,o] = Wv[o,:]·pooled[b,:] + bv[o]   (tiny) ----
__global__ __launch_bounds__(256) void k_gate(const float* __restrict__ pooled,
                                              const float* __restrict__ Wv,
                                              const float* __restrict__ bv,
                                              float* __restrict__ gate) {
    int t = blockIdx.x * 256 + threadIdx.x;       // 0..4095
    int b = t >> 9, o = t & (CC - 1);
    const float4* pr = (const float4*)(pooled + (size_t)b * CC);
    const float4* wr = (const float4*)(Wv + (size_t)o * CC);
    float acc = 0.f;
    #pragma unroll 8
    for (int i = 0; i < CC / 4; ++i) {
        float4 p = pr[i], w = wr[i];
        acc += p.x * w.x + p.y * w.y + p.z * w.z + p.w * w.w;
    }
    gate[t] = acc + bv[o];
}

// ---- G: out[b,c,hw] = x[b,c,hw] * gate[b,c]   (read+write: 536 MB) ----
// One (b,c) row per block: gate is a wave-uniform scalar load, body is a
// pure 64 KB in / 64 KB out stream, 16 independent float4 pairs per thread.
__global__ __launch_bounds__(256) void k_out(const float* __restrict__ x,
                                             const float* __restrict__ gate,
                                             float* __restrict__ out) {
    int bc = blockIdx.x;                          // 0..4095
    float g = gate[bc];
    const float4* xr = (const float4*)x   + (size_t)bc * HW4;
    float4*       orow = (float4*)out     + (size_t)bc * HW4;
    #pragma unroll 8
    for (int i = threadIdx.x; i < HW4; i += 256) {
        float4 v = xr[i];
        float4 o = { v.x * g, v.y * g, v.z * g, v.w * g };
        orow[i] = o;
    }
}

extern "C" void kernel_launch(void* const* d_in, const int* in_sizes, int n_in,
                              void* d_out, int out_size, void* d_ws, size_t ws_size,
                              hipStream_t stream) {
    const float* x   = (const float*)d_in[0];
    const float* ctx = (const float*)d_in[1];
    const float* Wq  = (const float*)d_in[2];
    const float* bq  = (const float*)d_in[3];
    const float* Wk  = (const float*)d_in[4];
    // d_in[5] = bk: per-batch constant in logits -> dropped (softmax shift-invariant)
    const float* Wv  = (const float*)d_in[6];
    const float* bv  = (const float*)d_in[7];
    float* out = (float*)d_out;

    // Workspace layout (floats): everything written before read, no zero-init needed.
    float* ws     = (float*)d_ws;
    float* q      = ws;                 // 4096
    float* qk     = ws + 4096;          // 4096
    float* pooled = ws + 8192;          // 4096
    float* gate   = ws + 12288;         // 4096
    float* logits = ws + 16384;         // 131072 (softmax runs in place -> attn)

    k_qproj  <<<  16, 256, 0, stream>>>(ctx, Wq, bq, q);
    k_qk     <<<  16, 256, 0, stream>>>(q, Wk, qk);
    k_logits <<< 512, 256, 0, stream>>>(x, qk, logits);
    k_softmax<<<  BB,1024, 0, stream>>>(logits);          // in place: logits -> attn
    k_pool   <<<4096, 256, 0, stream>>>(x, logits, pooled);
    k_gate   <<<  16, 256, 0, stream>>>(pooled, Wv, bv, gate);
    k_out    <<<4096, 256, 0, stream>>>(x, gate, out);
}